// Round 17
// baseline (119.495 us; speedup 1.0000x reference)
//
#include <hip/hip_runtime.h>
#include <hip/hip_bf16.h>
#include <math.h>

#define NN 25000
#define NE 100000
#define NTILES (NE / 16)   // 6250 edge tiles of 16
#define NBN 98             // ceil(NN/256)
#define NBE 391            // ceil(NE/256)
#define NBP 264            // ceil(2*33792/256)
#define NBC 391            // ceil(NE/256)

typedef __attribute__((ext_vector_type(8))) short short8;
typedef __attribute__((ext_vector_type(4))) float f32x4;

// pack 8 fp32 -> short8 of bf16 via HW packed convert (RTNE)
static __device__ __forceinline__ short8 pack_bf8(const float* p) {
  union { short8 s; unsigned int u[4]; } r;
#pragma unroll
  for (int q = 0; q < 4; q++)
    asm("v_cvt_pk_bf16_f32 %0, %1, %2" : "=v"(r.u[q]) : "v"(p[2 * q]), "v"(p[2 * q + 1]));
  return r.s;
}

// add 4 bf16 (packed in a uint2) into hv[0..4)
static __device__ __forceinline__ void bfadd4(float* hv, uint2 A) {
  hv[0] += __uint_as_float(A.x << 16);
  hv[1] += __uint_as_float(A.x & 0xffff0000u);
  hv[2] += __uint_as_float(A.y << 16);
  hv[3] += __uint_as_float(A.y & 0xffff0000u);
}

// ==== zero deg ====
__global__ void __launch_bounds__(256) k_zero(int* __restrict__ deg) {
  int n = blockIdx.x * 256 + threadIdx.x;
  if (n < NN) deg[n] = 0;
}

// ==== fused prep: node encoder | edge encoder(bf16 out) | W-pack | degree ====
__global__ void __launch_bounds__(256) k_prep(
    const float* __restrict__ x, const float* __restrict__ eattr,
    const int* __restrict__ ei,
    const float* __restrict__ We_node, const float* __restrict__ be_node,
    const float* __restrict__ We_edge, const float* __restrict__ be_edge,
    const float* __restrict__ root1, const float* __restrict__ bias1,
    const float* __restrict__ W1, const float* __restrict__ b1,
    const float* __restrict__ W2, const float* __restrict__ b2,
    float* __restrict__ h0, float* __restrict__ r1pre,
    __hip_bfloat16* __restrict__ eab,
    __hip_bfloat16* __restrict__ Bswz1, __hip_bfloat16* __restrict__ Bswz2,
    int* __restrict__ deg) {
  int b = blockIdx.x;
  int tid = threadIdx.x;
  if (b < NBN) {
    int n = b * 256 + tid;
    if (n >= NN) return;
    float xv[32], hv[32], rv[32];
#pragma unroll
    for (int i = 0; i < 8; i++) *(float4*)(xv + 4 * i) = *(const float4*)(x + n * 32 + 4 * i);
#pragma unroll
    for (int j = 0; j < 32; j++) hv[j] = be_node[j];
#pragma unroll
    for (int i = 0; i < 32; i++) {
      float xi = xv[i];
#pragma unroll
      for (int j = 0; j < 32; j++) hv[j] += xi * We_node[i * 32 + j];
    }
#pragma unroll
    for (int i = 0; i < 8; i++) *(float4*)(h0 + n * 32 + 4 * i) = *(float4*)(hv + 4 * i);
#pragma unroll
    for (int j = 0; j < 32; j++) rv[j] = bias1[j];
#pragma unroll
    for (int i = 0; i < 32; i++) {
      float hi = hv[i];
#pragma unroll
      for (int j = 0; j < 32; j++) rv[j] += hi * root1[i * 32 + j];
    }
#pragma unroll
    for (int i = 0; i < 8; i++) *(float4*)(r1pre + n * 32 + 4 * i) = *(float4*)(rv + 4 * i);
  } else if (b < NBN + NBE) {
    int e = (b - NBN) * 256 + tid;
    if (e >= NE) return;
    float av[16], ov[32];
#pragma unroll
    for (int i = 0; i < 4; i++) *(float4*)(av + 4 * i) = *(const float4*)(eattr + e * 16 + 4 * i);
#pragma unroll
    for (int j = 0; j < 32; j++) ov[j] = be_edge[j];
#pragma unroll
    for (int k = 0; k < 16; k++) {
      float ak = av[k];
#pragma unroll
      for (int j = 0; j < 32; j++) ov[j] += ak * We_edge[k * 32 + j];
    }
    short8* dst = (short8*)(eab + e * 32);
    dst[0] = pack_bf8(ov);
    dst[1] = pack_bf8(ov + 8);
    dst[2] = pack_bf8(ov + 16);
    dst[3] = pack_bf8(ov + 24);
  } else if (b < NBN + NBE + NBP) {
    int idx = (b - NBN - NBE) * 256 + tid;
    if (idx >= 2 * 33792) return;
    int sel = idx >= 33792;
    int r = idx - sel * 33792;
    int j = r & 7;
    int l = (r >> 3) & 63;
    int nt = (r >> 9) & 1;
    int t = r >> 10;
    int i = 8 * (l >> 4) + j;
    int o = nt * 16 + (l & 15);
    const float* W = sel ? W2 : W1;
    const float* bb = sel ? b2 : b1;
    float v = (t < 32) ? W[t * 1024 + i * 32 + o] : bb[i * 32 + o];
    (sel ? Bswz2 : Bswz1)[r] = __float2bfloat16(v);
  } else {
    int e = (b - NBN - NBE - NBP) * 256 + tid;
    if (e < NE) atomicAdd(&deg[ei[NE + e]], 1);
  }
}

// ==== scan stage 1: per-block sums of deg ====
__global__ void __launch_bounds__(256) k_scan1(const int* __restrict__ deg,
                                               int* __restrict__ bsum) {
  __shared__ int s[256];
  int tid = threadIdx.x;
  int n = blockIdx.x * 256 + tid;
  s[tid] = (n < NN) ? deg[n] : 0;
  __syncthreads();
  for (int d = 128; d > 0; d >>= 1) {
    if (tid < d) s[tid] += s[tid + d];
    __syncthreads();
  }
  if (tid == 0) bsum[blockIdx.x] = s[0];
}

// ==== scan stage 2: block-local exclusive scan + bsum prefix -> off/cursor ===
__global__ void __launch_bounds__(256) k_scan3(const int* __restrict__ deg,
                                               const int* __restrict__ bsum,
                                               int* __restrict__ off,
                                               int* __restrict__ cursor) {
  __shared__ int sb[128];
  __shared__ int s[256];
  int tid = threadIdx.x;
  if (tid < 128) sb[tid] = (tid < NBN) ? bsum[tid] : 0;
  int n = blockIdx.x * 256 + tid;
  int v = (n < NN) ? deg[n] : 0;
  s[tid] = v;
  __syncthreads();
  for (int d = 1; d < 128; d <<= 1) {
    int t = 0;
    if (tid < 128 && tid >= d) t = sb[tid - d];
    __syncthreads();
    if (tid < 128) sb[tid] += t;
    __syncthreads();
  }
  for (int d = 1; d < 256; d <<= 1) {
    int t = (tid >= d) ? s[tid - d] : 0;
    __syncthreads();
    s[tid] += t;
    __syncthreads();
  }
  int base = (blockIdx.x > 0) ? sb[blockIdx.x - 1] : 0;
  int excl = s[tid] - v + base;
  if (n < NN) { off[n] = excl; cursor[n] = excl; }
}

// ==== CSR fill: perm (edge->csr), srcs (csr->src node) ====
__global__ void k_csr_fill(const int* __restrict__ ei, int* __restrict__ cursor,
                           int* __restrict__ perm, int* __restrict__ srcs) {
  int e = blockIdx.x * blockDim.x + threadIdx.x;
  if (e >= NE) return;
  int d = ei[NE + e];
  int p = atomicAdd(&cursor[d], 1);
  perm[e] = p;
  srcs[p] = ei[e];
}

// ---- NNConv as MFMA GEMM; hybrid staging: steps 0..15 in LDS (32 KB), steps
// 16..31 + bias from L2-resident Bswz. 782 blocks -> 2 tiles/wave, ~12 waves/CU.
__global__ void __launch_bounds__(256) k_nnconv_mfma(
    const float* __restrict__ hin, const __hip_bfloat16* __restrict__ eab,
    const __hip_bfloat16* __restrict__ Bswz, const int* __restrict__ ei,
    const int* __restrict__ perm, __hip_bfloat16* __restrict__ msgbuf) {
  extern __shared__ short8 bsh[];   // 16 steps * 2 ntiles * 64 lanes = 32 KB
  int tid = threadIdx.x;
  {
    uint4* s4 = (uint4*)bsh;
    const uint4* g4 = (const uint4*)Bswz;
#pragma unroll
    for (int it = 0; it < 8; it++) s4[tid + 256 * it] = g4[tid + 256 * it];
  }
  __syncthreads();

  int wid = tid >> 6;
  int lane = tid & 63;
  int lrow = lane & 15;        // A row / C col
  int lk8 = (lane >> 4) * 8;   // k-offset of this lane's 8 A elems
  const short8* gb = (const short8*)Bswz;

  for (int tile = blockIdx.x * 4 + wid; tile < NTILES; tile += gridDim.x * 4) {
    int e0 = tile * 16;
    int e = e0 + lrow;
    int src = ei[e];
    float hf[8];
    *(float4*)(hf)     = *(const float4*)(hin + src * 32 + lk8);
    *(float4*)(hf + 4) = *(const float4*)(hin + src * 32 + lk8 + 4);
    unsigned int eau[16];
    {
      const uint4* ep = (const uint4*)(eab + e * 32);
#pragma unroll
      for (int q = 0; q < 4; q++) *(uint4*)(eau + 4 * q) = ep[q];
    }
    short8 af_bias = pack_bf8(hf);   // bias-step A frag, reused

    f32x4 a00 = {0.f, 0.f, 0.f, 0.f}, a01 = a00, a10 = a00, a11 = a00;
#pragma unroll
    for (int t = 0; t < 32; t++) {
      unsigned int u = eau[t >> 1];
      float et = (t & 1) ? __uint_as_float(u & 0xffff0000u) : __uint_as_float(u << 16);
      float pr[8];
#pragma unroll
      for (int j = 0; j < 8; j++) pr[j] = et * hf[j];
      short8 af = pack_bf8(pr);
      short8 b0, b1;
      if (t < 16) {
        b0 = bsh[(t * 2 + 0) * 64 + lane];
        b1 = bsh[(t * 2 + 1) * 64 + lane];
      } else {
        b0 = gb[(t * 2 + 0) * 64 + lane];
        b1 = gb[(t * 2 + 1) * 64 + lane];
      }
      if (t & 1) {
        a01 = __builtin_amdgcn_mfma_f32_16x16x32_bf16(af, b0, a01, 0, 0, 0);
        a11 = __builtin_amdgcn_mfma_f32_16x16x32_bf16(af, b1, a11, 0, 0, 0);
      } else {
        a00 = __builtin_amdgcn_mfma_f32_16x16x32_bf16(af, b0, a00, 0, 0, 0);
        a10 = __builtin_amdgcn_mfma_f32_16x16x32_bf16(af, b1, a10, 0, 0, 0);
      }
    }
    // bias K-step: A = h itself, B from global (L2-cached)
    {
      short8 b0 = gb[(32 * 2 + 0) * 64 + lane];
      short8 b1 = gb[(32 * 2 + 1) * 64 + lane];
      a00 = __builtin_amdgcn_mfma_f32_16x16x32_bf16(af_bias, b0, a00, 0, 0, 0);
      a10 = __builtin_amdgcn_mfma_f32_16x16x32_bf16(af_bias, b1, a10, 0, 0, 0);
    }
    f32x4 c0 = a00 + a01;
    f32x4 c1 = a10 + a11;
    int r0 = (lane >> 4) * 4;
#pragma unroll
    for (int r = 0; r < 4; r++) {
      int p = perm[e0 + r0 + r];
      __hip_bfloat16* mp = msgbuf + p * 32 + lrow;
      mp[0]  = __float2bfloat16(c0[r]);
      mp[16] = __float2bfloat16(c1[r]);
    }
  }
}

// ---- node pass 1 (8 threads/node): stream bf16 msgbuf, butterfly, GEMM ------
__global__ void __launch_bounds__(256) k_node1(
    const float* __restrict__ r1pre, const __hip_bfloat16* __restrict__ msgbuf,
    const int* __restrict__ off, const int* __restrict__ deg,
    const float* __restrict__ Wl, const float* __restrict__ bl,
    const float* __restrict__ Wr, const float* __restrict__ br,
    float* __restrict__ xl, float* __restrict__ xr) {
  int t = blockIdx.x * blockDim.x + threadIdx.x;
  if (t >= 8 * NN) return;
  int n = t >> 3, sub = t & 7;
  int co = sub * 4;
  float hv[4];
  *(float4*)hv = *(const float4*)(r1pre + n * 32 + co);
  int o0 = off[n], o1 = o0 + deg[n];
  int idx = o0;
  for (; idx + 1 < o1; idx += 2) {
    uint2 A = *(const uint2*)(msgbuf + idx * 32 + co);
    uint2 B = *(const uint2*)(msgbuf + (idx + 1) * 32 + co);
    bfadd4(hv, A);
    bfadd4(hv, B);
  }
  if (idx < o1) {
    uint2 A = *(const uint2*)(msgbuf + idx * 32 + co);
    bfadd4(hv, A);
  }
#pragma unroll
  for (int j = 0; j < 4; j++) hv[j] = fmaxf(hv[j], 0.f);
  // butterfly: reconstruct full h1[32] across the 8-thread group
  float b8[8], b16[16], h1[32];
#pragma unroll
  for (int j = 0; j < 4; j++) {
    float o = __shfl_xor(hv[j], 1);
    b8[j]     = (sub & 1) ? o : hv[j];
    b8[4 + j] = (sub & 1) ? hv[j] : o;
  }
#pragma unroll
  for (int j = 0; j < 8; j++) {
    float o = __shfl_xor(b8[j], 2);
    b16[j]     = (sub & 2) ? o : b8[j];
    b16[8 + j] = (sub & 2) ? b8[j] : o;
  }
#pragma unroll
  for (int j = 0; j < 16; j++) {
    float o = __shfl_xor(b16[j], 4);
    h1[j]      = (sub & 4) ? o : b16[j];
    h1[16 + j] = (sub & 4) ? b16[j] : o;
  }
  // each thread computes 8 output cols: sub<4 -> xl[jo..jo+8), else xr
  const float* W = (sub < 4) ? Wl : Wr;
  const float* bb = (sub < 4) ? bl : br;
  int jo = (sub & 3) * 8;
  float ov[8];
#pragma unroll
  for (int j = 0; j < 8; j++) ov[j] = bb[jo + j];
#pragma unroll
  for (int i = 0; i < 32; i++) {
    float hi = h1[i];
#pragma unroll
    for (int j = 0; j < 8; j++) ov[j] += hi * W[i * 32 + jo + j];
  }
  float* dst = ((sub < 4) ? xl : xr) + n * 32 + jo;
  *(float4*)(dst)     = *(float4*)(ov);
  *(float4*)(dst + 4) = *(float4*)(ov + 4);
}

// ---- GAT node pass (8 threads/node = 1 per half-head): single-pass softmax --
__global__ void __launch_bounds__(256) k_gat_node(
    const int* __restrict__ srcs,
    const float* __restrict__ xl, const float* __restrict__ xr,
    const int* __restrict__ off, const int* __restrict__ deg,
    const float* __restrict__ att, const float* __restrict__ bias_gat,
    float* __restrict__ h2) {
  int t = blockIdx.x * blockDim.x + threadIdx.x;
  if (t >= 8 * NN) return;
  int n = t >> 3, sub = t & 7;
  int co = sub * 4;                       // column offset within [0,32)
  float xrv[4], attv[4], xself[4];
  *(float4*)(xrv)   = *(const float4*)(xr + n * 32 + co);
  *(float4*)(attv)  = *(const float4*)(att + co);
  *(float4*)(xself) = *(const float4*)(xl + n * 32 + co);
  // self-loop
  float slgp = 0.f;
#pragma unroll
  for (int dg = 0; dg < 4; dg++) {
    float v = xself[dg] + xrv[dg];
    v = (v > 0.f) ? v : 0.2f * v;
    slgp += v * attv[dg];
  }
  float slg = slgp + __shfl_xor(slgp, 1);
  float w0 = __expf(slg);
  float den = w0;
  float accv[4];
#pragma unroll
  for (int dg = 0; dg < 4; dg++) accv[dg] = w0 * xself[dg];
  int o0 = off[n], o1 = o0 + deg[n];
  int idx = o0;
  for (; idx + 1 < o1; idx += 2) {
    int s0 = srcs[idx], s1 = srcs[idx + 1];
    float xa[4], xb[4];
    *(float4*)(xa) = *(const float4*)(xl + s0 * 32 + co);
    *(float4*)(xb) = *(const float4*)(xl + s1 * 32 + co);
    float lga = 0.f, lgb = 0.f;
#pragma unroll
    for (int dg = 0; dg < 4; dg++) {
      float va = xa[dg] + xrv[dg];
      va = (va > 0.f) ? va : 0.2f * va;
      lga += va * attv[dg];
      float vb = xb[dg] + xrv[dg];
      vb = (vb > 0.f) ? vb : 0.2f * vb;
      lgb += vb * attv[dg];
    }
    float la = lga + __shfl_xor(lga, 1);
    float lb = lgb + __shfl_xor(lgb, 1);
    float wa = __expf(la), wb = __expf(lb);
    den += wa + wb;
#pragma unroll
    for (int dg = 0; dg < 4; dg++) accv[dg] += wa * xa[dg] + wb * xb[dg];
  }
  if (idx < o1) {
    int s0 = srcs[idx];
    float xa[4];
    *(float4*)(xa) = *(const float4*)(xl + s0 * 32 + co);
    float lga = 0.f;
#pragma unroll
    for (int dg = 0; dg < 4; dg++) {
      float va = xa[dg] + xrv[dg];
      va = (va > 0.f) ? va : 0.2f * va;
      lga += va * attv[dg];
    }
    float la = lga + __shfl_xor(lga, 1);
    float wa = __expf(la);
    den += wa;
#pragma unroll
    for (int dg = 0; dg < 4; dg++) accv[dg] += wa * xa[dg];
  }
  float sc = 1.f / (den + 1e-16f);
  float hv[4];
#pragma unroll
  for (int dg = 0; dg < 4; dg++)
    hv[dg] = fmaxf(accv[dg] * sc + bias_gat[co + dg], 0.f);
  *(float4*)(h2 + n * 32 + co) = *(float4*)(hv);
}

// ---- node pass 2 (8 threads/node): root2 GEMM + stream + classifier ---------
__global__ void __launch_bounds__(256) k_node2(
    const float* __restrict__ h2, const __hip_bfloat16* __restrict__ msgbuf,
    const int* __restrict__ off, const int* __restrict__ deg,
    const float* __restrict__ root2, const float* __restrict__ bias2,
    const float* __restrict__ Wlin, const float* __restrict__ blin,
    float* __restrict__ out) {
  int t = blockIdx.x * blockDim.x + threadIdx.x;
  if (t >= 8 * NN) return;
  int n = t >> 3, sub = t & 7;
  int co = sub * 4;
  float h2v[32];   // full row, 8 threads share via L1
#pragma unroll
  for (int i = 0; i < 8; i++) *(float4*)(h2v + 4 * i) = *(const float4*)(h2 + n * 32 + 4 * i);
  float rv[4];
#pragma unroll
  for (int j = 0; j < 4; j++) rv[j] = bias2[co + j];
#pragma unroll
  for (int i = 0; i < 32; i++) {
    float hi = h2v[i];
#pragma unroll
    for (int j = 0; j < 4; j++) rv[j] += hi * root2[i * 32 + co + j];
  }
  int o0 = off[n], o1 = o0 + deg[n];
  int idx = o0;
  for (; idx + 1 < o1; idx += 2) {
    uint2 A = *(const uint2*)(msgbuf + idx * 32 + co);
    uint2 B = *(const uint2*)(msgbuf + (idx + 1) * 32 + co);
    bfadd4(rv, A);
    bfadd4(rv, B);
  }
  if (idx < o1) {
    uint2 A = *(const uint2*)(msgbuf + idx * 32 + co);
    bfadd4(rv, A);
  }
#pragma unroll
  for (int j = 0; j < 4; j++) rv[j] = fmaxf(rv[j], 0.f);
  float ov[10];
#pragma unroll
  for (int c = 0; c < 10; c++) ov[c] = 0.f;
#pragma unroll
  for (int j = 0; j < 4; j++) {
    float hj = rv[j];
#pragma unroll
    for (int c = 0; c < 10; c++) ov[c] += hj * Wlin[(co + j) * 10 + c];
  }
#pragma unroll
  for (int c = 0; c < 10; c++) ov[c] += __shfl_xor(ov[c], 1);
#pragma unroll
  for (int c = 0; c < 10; c++) ov[c] += __shfl_xor(ov[c], 2);
#pragma unroll
  for (int c = 0; c < 10; c++) ov[c] += __shfl_xor(ov[c], 4);
  // predicated writes, compile-time indices: thread sub writes classes 2sub,2sub+1
#pragma unroll
  for (int c = 0; c < 10; c++) {
    if ((c >> 1) == sub) out[n * 10 + c] = ov[c] + blin[c];
  }
}

extern "C" void kernel_launch(void* const* d_in, const int* in_sizes, int n_in,
                              void* d_out, int out_size, void* d_ws, size_t ws_size,
                              hipStream_t stream) {
  const float* x         = (const float*)d_in[0];
  const float* edge_attr = (const float*)d_in[1];
  const int*   ei        = (const int*)d_in[2];   // [2,E]: src = ei, dst = ei+NE
  const float* We_node   = (const float*)d_in[3];
  const float* be_node   = (const float*)d_in[4];
  const float* We_edge   = (const float*)d_in[5];
  const float* be_edge   = (const float*)d_in[6];
  const float* W1_nn     = (const float*)d_in[7];
  const float* b1_nn     = (const float*)d_in[8];
  const float* root1     = (const float*)d_in[9];
  const float* bias1     = (const float*)d_in[10];
  const float* Wl        = (const float*)d_in[11];
  const float* bl        = (const float*)d_in[12];
  const float* Wr        = (const float*)d_in[13];
  const float* br        = (const float*)d_in[14];
  const float* att       = (const float*)d_in[15];
  const float* bias_gat  = (const float*)d_in[16];
  const float* W2_nn     = (const float*)d_in[17];
  const float* b2_nn     = (const float*)d_in[18];
  const float* root2     = (const float*)d_in[19];
  const float* bias2     = (const float*)d_in[20];
  const float* Wlin      = (const float*)d_in[21];
  const float* blin      = (const float*)d_in[22];
  float* out = (float*)d_out;

  float* ws = (float*)d_ws;
  float* h0h2  = ws;                 // NN*32 (h0, later h2)
  float* easlab = h0h2 + NN * 32;    // NE*32 floats reserved; bf16 ea in half
  __hip_bfloat16* eab = (__hip_bfloat16*)easlab;     // NE*32 bf16
  float* r1pre = easlab + NE * 32;   // NN*32
  float* xl    = r1pre + NN * 32;    // NN*32
  float* xr    = xl + NN * 32;       // NN*32
  float* mslab = xr + NN * 32;       // NE*32 floats reserved; bf16 msgbuf
  __hip_bfloat16* msgbuf = (__hip_bfloat16*)mslab;   // NE*32 bf16 (CSR order)
  float* fend  = mslab + NE * 32;
  __hip_bfloat16* Bswz1 = (__hip_bfloat16*)fend;            // 33792 bf16
  __hip_bfloat16* Bswz2 = (__hip_bfloat16*)(fend + 17000);  // 33792 bf16
  int* deg    = (int*)(fend + 34000);   // NN
  int* off    = deg + NN;               // NN
  int* cursor = off + NN;               // NN
  int* bsum   = cursor + NN;            // 128
  int* perm   = bsum + 128;             // NE
  int* srcs   = perm + NE;              // NE

  const int B = 256;
  k_zero<<<NBN, B, 0, stream>>>(deg);
  k_prep<<<NBN + NBE + NBP + NBC, B, 0, stream>>>(
      x, edge_attr, ei, We_node, be_node, We_edge, be_edge, root1, bias1,
      W1_nn, b1_nn, W2_nn, b2_nn, h0h2, r1pre, eab, Bswz1, Bswz2, deg);
  k_scan1<<<NBN, B, 0, stream>>>(deg, bsum);
  k_scan3<<<NBN, B, 0, stream>>>(deg, bsum, off, cursor);
  k_csr_fill<<<(NE + B - 1) / B, B, 0, stream>>>(ei, cursor, perm, srcs);
  k_nnconv_mfma<<<782, B, 32768, stream>>>(h0h2, eab, Bswz1, ei, perm, msgbuf);
  k_node1<<<(8 * NN + B - 1) / B, B, 0, stream>>>(r1pre, msgbuf, off, deg, Wl, bl, Wr, br, xl, xr);
  k_gat_node<<<(8 * NN + B - 1) / B, B, 0, stream>>>(srcs, xl, xr, off, deg, att, bias_gat, h0h2);
  k_nnconv_mfma<<<782, B, 32768, stream>>>(h0h2, eab, Bswz2, ei, perm, msgbuf);
  k_node2<<<(8 * NN + B - 1) / B, B, 0, stream>>>(h0h2, msgbuf, off, deg, root2, bias2, Wlin, blin, out);
}

// Round 19
// 103.254 us; speedup vs baseline: 1.1573x; 1.1573x over previous
//
#include <hip/hip_runtime.h>
#include <hip/hip_bf16.h>
#include <math.h>

#define NN 25000
#define NE 100000
#define NTILES (NE / 16)   // 6250 edge tiles of 16
#define NBN 98             // ceil(NN/256)
#define NBE 391            // ceil(NE/256)
#define NBP 264            // ceil(2*33792/256)
#define NBC 391            // ceil(NE/256)

typedef __attribute__((ext_vector_type(8))) short short8;
typedef __attribute__((ext_vector_type(4))) float f32x4;

// pack 8 fp32 -> short8 of bf16 via HW packed convert (RTNE)
static __device__ __forceinline__ short8 pack_bf8(const float* p) {
  union { short8 s; unsigned int u[4]; } r;
#pragma unroll
  for (int q = 0; q < 4; q++)
    asm("v_cvt_pk_bf16_f32 %0, %1, %2" : "=v"(r.u[q]) : "v"(p[2 * q]), "v"(p[2 * q + 1]));
  return r.s;
}

// add 4 bf16 (packed in a uint2) into hv[0..4)
static __device__ __forceinline__ void bfadd4(float* hv, uint2 A) {
  hv[0] += __uint_as_float(A.x << 16);
  hv[1] += __uint_as_float(A.x & 0xffff0000u);
  hv[2] += __uint_as_float(A.y << 16);
  hv[3] += __uint_as_float(A.y & 0xffff0000u);
}

// ==== zero deg ====
__global__ void __launch_bounds__(256) k_zero(int* __restrict__ deg) {
  int n = blockIdx.x * 256 + threadIdx.x;
  if (n < NN) deg[n] = 0;
}

// ==== fused prep: node encoder | edge encoder(bf16 out) | W-pack | degree ====
__global__ void __launch_bounds__(256) k_prep(
    const float* __restrict__ x, const float* __restrict__ eattr,
    const int* __restrict__ ei,
    const float* __restrict__ We_node, const float* __restrict__ be_node,
    const float* __restrict__ We_edge, const float* __restrict__ be_edge,
    const float* __restrict__ root1, const float* __restrict__ bias1,
    const float* __restrict__ W1, const float* __restrict__ b1,
    const float* __restrict__ W2, const float* __restrict__ b2,
    float* __restrict__ h0, float* __restrict__ r1pre,
    __hip_bfloat16* __restrict__ eab,
    __hip_bfloat16* __restrict__ Bswz1, __hip_bfloat16* __restrict__ Bswz2,
    int* __restrict__ deg) {
  int b = blockIdx.x;
  int tid = threadIdx.x;
  if (b < NBN) {
    int n = b * 256 + tid;
    if (n >= NN) return;
    float xv[32], hv[32], rv[32];
#pragma unroll
    for (int i = 0; i < 8; i++) *(float4*)(xv + 4 * i) = *(const float4*)(x + n * 32 + 4 * i);
#pragma unroll
    for (int j = 0; j < 32; j++) hv[j] = be_node[j];
#pragma unroll
    for (int i = 0; i < 32; i++) {
      float xi = xv[i];
#pragma unroll
      for (int j = 0; j < 32; j++) hv[j] += xi * We_node[i * 32 + j];
    }
#pragma unroll
    for (int i = 0; i < 8; i++) *(float4*)(h0 + n * 32 + 4 * i) = *(float4*)(hv + 4 * i);
#pragma unroll
    for (int j = 0; j < 32; j++) rv[j] = bias1[j];
#pragma unroll
    for (int i = 0; i < 32; i++) {
      float hi = hv[i];
#pragma unroll
      for (int j = 0; j < 32; j++) rv[j] += hi * root1[i * 32 + j];
    }
#pragma unroll
    for (int i = 0; i < 8; i++) *(float4*)(r1pre + n * 32 + 4 * i) = *(float4*)(rv + 4 * i);
  } else if (b < NBN + NBE) {
    int e = (b - NBN) * 256 + tid;
    if (e >= NE) return;
    float av[16], ov[32];
#pragma unroll
    for (int i = 0; i < 4; i++) *(float4*)(av + 4 * i) = *(const float4*)(eattr + e * 16 + 4 * i);
#pragma unroll
    for (int j = 0; j < 32; j++) ov[j] = be_edge[j];
#pragma unroll
    for (int k = 0; k < 16; k++) {
      float ak = av[k];
#pragma unroll
      for (int j = 0; j < 32; j++) ov[j] += ak * We_edge[k * 32 + j];
    }
    short8* dst = (short8*)(eab + e * 32);
    dst[0] = pack_bf8(ov);
    dst[1] = pack_bf8(ov + 8);
    dst[2] = pack_bf8(ov + 16);
    dst[3] = pack_bf8(ov + 24);
  } else if (b < NBN + NBE + NBP) {
    int idx = (b - NBN - NBE) * 256 + tid;
    if (idx >= 2 * 33792) return;
    int sel = idx >= 33792;
    int r = idx - sel * 33792;
    int j = r & 7;
    int l = (r >> 3) & 63;
    int nt = (r >> 9) & 1;
    int t = r >> 10;
    int i = 8 * (l >> 4) + j;
    int o = nt * 16 + (l & 15);
    const float* W = sel ? W2 : W1;
    const float* bb = sel ? b2 : b1;
    float v = (t < 32) ? W[t * 1024 + i * 32 + o] : bb[i * 32 + o];
    (sel ? Bswz2 : Bswz1)[r] = __float2bfloat16(v);
  } else {
    int e = (b - NBN - NBE - NBP) * 256 + tid;
    if (e < NE) atomicAdd(&deg[ei[NE + e]], 1);
  }
}

// ==== scan stage 1: per-block sums of deg ====
__global__ void __launch_bounds__(256) k_scan1(const int* __restrict__ deg,
                                               int* __restrict__ bsum) {
  __shared__ int s[256];
  int tid = threadIdx.x;
  int n = blockIdx.x * 256 + tid;
  s[tid] = (n < NN) ? deg[n] : 0;
  __syncthreads();
  for (int d = 128; d > 0; d >>= 1) {
    if (tid < d) s[tid] += s[tid + d];
    __syncthreads();
  }
  if (tid == 0) bsum[blockIdx.x] = s[0];
}

// ==== scan stage 2: block-local exclusive scan + bsum prefix -> off/cursor ===
__global__ void __launch_bounds__(256) k_scan3(const int* __restrict__ deg,
                                               const int* __restrict__ bsum,
                                               int* __restrict__ off,
                                               int* __restrict__ cursor) {
  __shared__ int sb[128];
  __shared__ int s[256];
  int tid = threadIdx.x;
  if (tid < 128) sb[tid] = (tid < NBN) ? bsum[tid] : 0;
  int n = blockIdx.x * 256 + tid;
  int v = (n < NN) ? deg[n] : 0;
  s[tid] = v;
  __syncthreads();
  for (int d = 1; d < 128; d <<= 1) {
    int t = 0;
    if (tid < 128 && tid >= d) t = sb[tid - d];
    __syncthreads();
    if (tid < 128) sb[tid] += t;
    __syncthreads();
  }
  for (int d = 1; d < 256; d <<= 1) {
    int t = (tid >= d) ? s[tid - d] : 0;
    __syncthreads();
    s[tid] += t;
    __syncthreads();
  }
  int base = (blockIdx.x > 0) ? sb[blockIdx.x - 1] : 0;
  int excl = s[tid] - v + base;
  if (n < NN) { off[n] = excl; cursor[n] = excl; }
}

// ==== CSR fill: perm (edge->csr), srcs (csr->src node) ====
__global__ void k_csr_fill(const int* __restrict__ ei, int* __restrict__ cursor,
                           int* __restrict__ perm, int* __restrict__ srcs) {
  int e = blockIdx.x * blockDim.x + threadIdx.x;
  if (e >= NE) return;
  int d = ei[NE + e];
  int p = atomicAdd(&cursor[d], 1);
  perm[e] = p;
  srcs[p] = ei[e];
}

// ---- NNConv as MFMA GEMM (R16-exact); bf16 ea; bf16 msgbuf in CSR order -----
__global__ void __launch_bounds__(256) k_nnconv_mfma(
    const float* __restrict__ hin, const __hip_bfloat16* __restrict__ eab,
    const __hip_bfloat16* __restrict__ Bswz, const int* __restrict__ ei,
    const int* __restrict__ perm, __hip_bfloat16* __restrict__ msgbuf) {
  extern __shared__ short8 bsh[];   // 32 steps * 2 ntiles * 64 lanes = 64 KB
  int tid = threadIdx.x;
  {
    uint4* s4 = (uint4*)bsh;
    const uint4* g4 = (const uint4*)Bswz;
#pragma unroll
    for (int it = 0; it < 16; it++) s4[tid + 256 * it] = g4[tid + 256 * it];
  }
  __syncthreads();

  int wid = tid >> 6;
  int lane = tid & 63;
  int lrow = lane & 15;        // A row / C col
  int lk8 = (lane >> 4) * 8;   // k-offset of this lane's 8 A elems
  const short8* gb = (const short8*)Bswz;

  for (int tile = blockIdx.x * 4 + wid; tile < NTILES; tile += gridDim.x * 4) {
    int e0 = tile * 16;
    int e = e0 + lrow;
    int src = ei[e];
    float hf[8];
    *(float4*)(hf)     = *(const float4*)(hin + src * 32 + lk8);
    *(float4*)(hf + 4) = *(const float4*)(hin + src * 32 + lk8 + 4);
    unsigned int eau[16];
    {
      const uint4* ep = (const uint4*)(eab + e * 32);
#pragma unroll
      for (int q = 0; q < 4; q++) *(uint4*)(eau + 4 * q) = ep[q];
    }
    short8 af_bias = pack_bf8(hf);   // bias-step A frag, reused

    f32x4 a00 = {0.f, 0.f, 0.f, 0.f}, a01 = a00, a10 = a00, a11 = a00;
#pragma unroll
    for (int t = 0; t < 32; t++) {
      unsigned int u = eau[t >> 1];
      float et = (t & 1) ? __uint_as_float(u & 0xffff0000u) : __uint_as_float(u << 16);
      float pr[8];
#pragma unroll
      for (int j = 0; j < 8; j++) pr[j] = et * hf[j];
      short8 af = pack_bf8(pr);
      short8 b0 = bsh[(t * 2 + 0) * 64 + lane];
      short8 b1 = bsh[(t * 2 + 1) * 64 + lane];
      if (t & 1) {
        a01 = __builtin_amdgcn_mfma_f32_16x16x32_bf16(af, b0, a01, 0, 0, 0);
        a11 = __builtin_amdgcn_mfma_f32_16x16x32_bf16(af, b1, a11, 0, 0, 0);
      } else {
        a00 = __builtin_amdgcn_mfma_f32_16x16x32_bf16(af, b0, a00, 0, 0, 0);
        a10 = __builtin_amdgcn_mfma_f32_16x16x32_bf16(af, b1, a10, 0, 0, 0);
      }
    }
    // bias K-step: A = h itself, B from global (L2-cached)
    {
      short8 b0 = gb[(32 * 2 + 0) * 64 + lane];
      short8 b1 = gb[(32 * 2 + 1) * 64 + lane];
      a00 = __builtin_amdgcn_mfma_f32_16x16x32_bf16(af_bias, b0, a00, 0, 0, 0);
      a10 = __builtin_amdgcn_mfma_f32_16x16x32_bf16(af_bias, b1, a10, 0, 0, 0);
    }
    f32x4 c0 = a00 + a01;
    f32x4 c1 = a10 + a11;
    int r0 = (lane >> 4) * 4;
#pragma unroll
    for (int r = 0; r < 4; r++) {
      int p = perm[e0 + r0 + r];
      __hip_bfloat16* mp = msgbuf + p * 32 + lrow;
      mp[0]  = __float2bfloat16(c0[r]);
      mp[16] = __float2bfloat16(c1[r]);
    }
  }
}

// ---- node pass 1 (8 threads/node): stream bf16 msgbuf, butterfly, GEMM ------
__global__ void __launch_bounds__(256) k_node1(
    const float* __restrict__ r1pre, const __hip_bfloat16* __restrict__ msgbuf,
    const int* __restrict__ off, const int* __restrict__ deg,
    const float* __restrict__ Wl, const float* __restrict__ bl,
    const float* __restrict__ Wr, const float* __restrict__ br,
    float* __restrict__ xl, float* __restrict__ xr) {
  int t = blockIdx.x * blockDim.x + threadIdx.x;
  if (t >= 8 * NN) return;
  int n = t >> 3, sub = t & 7;
  int co = sub * 4;
  float hv[4];
  *(float4*)hv = *(const float4*)(r1pre + n * 32 + co);
  int o0 = off[n], o1 = o0 + deg[n];
  int idx = o0;
  for (; idx + 1 < o1; idx += 2) {
    uint2 A = *(const uint2*)(msgbuf + idx * 32 + co);
    uint2 B = *(const uint2*)(msgbuf + (idx + 1) * 32 + co);
    bfadd4(hv, A);
    bfadd4(hv, B);
  }
  if (idx < o1) {
    uint2 A = *(const uint2*)(msgbuf + idx * 32 + co);
    bfadd4(hv, A);
  }
#pragma unroll
  for (int j = 0; j < 4; j++) hv[j] = fmaxf(hv[j], 0.f);
  // butterfly: reconstruct full h1[32] across the 8-thread group
  float b8[8], b16[16], h1[32];
#pragma unroll
  for (int j = 0; j < 4; j++) {
    float o = __shfl_xor(hv[j], 1);
    b8[j]     = (sub & 1) ? o : hv[j];
    b8[4 + j] = (sub & 1) ? hv[j] : o;
  }
#pragma unroll
  for (int j = 0; j < 8; j++) {
    float o = __shfl_xor(b8[j], 2);
    b16[j]     = (sub & 2) ? o : b8[j];
    b16[8 + j] = (sub & 2) ? b8[j] : o;
  }
#pragma unroll
  for (int j = 0; j < 16; j++) {
    float o = __shfl_xor(b16[j], 4);
    h1[j]      = (sub & 4) ? o : b16[j];
    h1[16 + j] = (sub & 4) ? b16[j] : o;
  }
  // each thread computes 8 output cols: sub<4 -> xl[jo..jo+8), else xr
  const float* W = (sub < 4) ? Wl : Wr;
  const float* bb = (sub < 4) ? bl : br;
  int jo = (sub & 3) * 8;
  float ov[8];
#pragma unroll
  for (int j = 0; j < 8; j++) ov[j] = bb[jo + j];
#pragma unroll
  for (int i = 0; i < 32; i++) {
    float hi = h1[i];
#pragma unroll
    for (int j = 0; j < 8; j++) ov[j] += hi * W[i * 32 + jo + j];
  }
  float* dst = ((sub < 4) ? xl : xr) + n * 32 + jo;
  *(float4*)(dst)     = *(float4*)(ov);
  *(float4*)(dst + 4) = *(float4*)(ov + 4);
}

// ---- GAT node pass (8 threads/node = 1 per half-head): single-pass softmax --
__global__ void __launch_bounds__(256) k_gat_node(
    const int* __restrict__ srcs,
    const float* __restrict__ xl, const float* __restrict__ xr,
    const int* __restrict__ off, const int* __restrict__ deg,
    const float* __restrict__ att, const float* __restrict__ bias_gat,
    float* __restrict__ h2) {
  int t = blockIdx.x * blockDim.x + threadIdx.x;
  if (t >= 8 * NN) return;
  int n = t >> 3, sub = t & 7;
  int co = sub * 4;                       // column offset within [0,32)
  float xrv[4], attv[4], xself[4];
  *(float4*)(xrv)   = *(const float4*)(xr + n * 32 + co);
  *(float4*)(attv)  = *(const float4*)(att + co);
  *(float4*)(xself) = *(const float4*)(xl + n * 32 + co);
  // self-loop
  float slgp = 0.f;
#pragma unroll
  for (int dg = 0; dg < 4; dg++) {
    float v = xself[dg] + xrv[dg];
    v = (v > 0.f) ? v : 0.2f * v;
    slgp += v * attv[dg];
  }
  float slg = slgp + __shfl_xor(slgp, 1);
  float w0 = __expf(slg);
  float den = w0;
  float accv[4];
#pragma unroll
  for (int dg = 0; dg < 4; dg++) accv[dg] = w0 * xself[dg];
  int o0 = off[n], o1 = o0 + deg[n];
  int idx = o0;
  for (; idx + 1 < o1; idx += 2) {
    int s0 = srcs[idx], s1 = srcs[idx + 1];
    float xa[4], xb[4];
    *(float4*)(xa) = *(const float4*)(xl + s0 * 32 + co);
    *(float4*)(xb) = *(const float4*)(xl + s1 * 32 + co);
    float lga = 0.f, lgb = 0.f;
#pragma unroll
    for (int dg = 0; dg < 4; dg++) {
      float va = xa[dg] + xrv[dg];
      va = (va > 0.f) ? va : 0.2f * va;
      lga += va * attv[dg];
      float vb = xb[dg] + xrv[dg];
      vb = (vb > 0.f) ? vb : 0.2f * vb;
      lgb += vb * attv[dg];
    }
    float la = lga + __shfl_xor(lga, 1);
    float lb = lgb + __shfl_xor(lgb, 1);
    float wa = __expf(la), wb = __expf(lb);
    den += wa + wb;
#pragma unroll
    for (int dg = 0; dg < 4; dg++) accv[dg] += wa * xa[dg] + wb * xb[dg];
  }
  if (idx < o1) {
    int s0 = srcs[idx];
    float xa[4];
    *(float4*)(xa) = *(const float4*)(xl + s0 * 32 + co);
    float lga = 0.f;
#pragma unroll
    for (int dg = 0; dg < 4; dg++) {
      float va = xa[dg] + xrv[dg];
      va = (va > 0.f) ? va : 0.2f * va;
      lga += va * attv[dg];
    }
    float la = lga + __shfl_xor(lga, 1);
    float wa = __expf(la);
    den += wa;
#pragma unroll
    for (int dg = 0; dg < 4; dg++) accv[dg] += wa * xa[dg];
  }
  float sc = 1.f / (den + 1e-16f);
  float hv[4];
#pragma unroll
  for (int dg = 0; dg < 4; dg++)
    hv[dg] = fmaxf(accv[dg] * sc + bias_gat[co + dg], 0.f);
  *(float4*)(h2 + n * 32 + co) = *(float4*)(hv);
}

// ---- node pass 2 (8 threads/node): root2 GEMM + stream + classifier ---------
__global__ void __launch_bounds__(256) k_node2(
    const float* __restrict__ h2, const __hip_bfloat16* __restrict__ msgbuf,
    const int* __restrict__ off, const int* __restrict__ deg,
    const float* __restrict__ root2, const float* __restrict__ bias2,
    const float* __restrict__ Wlin, const float* __restrict__ blin,
    float* __restrict__ out) {
  int t = blockIdx.x * blockDim.x + threadIdx.x;
  if (t >= 8 * NN) return;
  int n = t >> 3, sub = t & 7;
  int co = sub * 4;
  float h2v[32];   // full row, 8 threads share via L1
#pragma unroll
  for (int i = 0; i < 8; i++) *(float4*)(h2v + 4 * i) = *(const float4*)(h2 + n * 32 + 4 * i);
  float rv[4];
#pragma unroll
  for (int j = 0; j < 4; j++) rv[j] = bias2[co + j];
#pragma unroll
  for (int i = 0; i < 32; i++) {
    float hi = h2v[i];
#pragma unroll
    for (int j = 0; j < 4; j++) rv[j] += hi * root2[i * 32 + co + j];
  }
  int o0 = off[n], o1 = o0 + deg[n];
  int idx = o0;
  for (; idx + 1 < o1; idx += 2) {
    uint2 A = *(const uint2*)(msgbuf + idx * 32 + co);
    uint2 B = *(const uint2*)(msgbuf + (idx + 1) * 32 + co);
    bfadd4(rv, A);
    bfadd4(rv, B);
  }
  if (idx < o1) {
    uint2 A = *(const uint2*)(msgbuf + idx * 32 + co);
    bfadd4(rv, A);
  }
#pragma unroll
  for (int j = 0; j < 4; j++) rv[j] = fmaxf(rv[j], 0.f);
  float ov[10];
#pragma unroll
  for (int c = 0; c < 10; c++) ov[c] = 0.f;
#pragma unroll
  for (int j = 0; j < 4; j++) {
    float hj = rv[j];
#pragma unroll
    for (int c = 0; c < 10; c++) ov[c] += hj * Wlin[(co + j) * 10 + c];
  }
#pragma unroll
  for (int c = 0; c < 10; c++) ov[c] += __shfl_xor(ov[c], 1);
#pragma unroll
  for (int c = 0; c < 10; c++) ov[c] += __shfl_xor(ov[c], 2);
#pragma unroll
  for (int c = 0; c < 10; c++) ov[c] += __shfl_xor(ov[c], 4);
  // predicated writes, compile-time indices: thread sub writes classes 2sub,2sub+1
#pragma unroll
  for (int c = 0; c < 10; c++) {
    if ((c >> 1) == sub) out[n * 10 + c] = ov[c] + blin[c];
  }
}

extern "C" void kernel_launch(void* const* d_in, const int* in_sizes, int n_in,
                              void* d_out, int out_size, void* d_ws, size_t ws_size,
                              hipStream_t stream) {
  const float* x         = (const float*)d_in[0];
  const float* edge_attr = (const float*)d_in[1];
  const int*   ei        = (const int*)d_in[2];   // [2,E]: src = ei, dst = ei+NE
  const float* We_node   = (const float*)d_in[3];
  const float* be_node   = (const float*)d_in[4];
  const float* We_edge   = (const float*)d_in[5];
  const float* be_edge   = (const float*)d_in[6];
  const float* W1_nn     = (const float*)d_in[7];
  const float* b1_nn     = (const float*)d_in[8];
  const float* root1     = (const float*)d_in[9];
  const float* bias1     = (const float*)d_in[10];
  const float* Wl        = (const float*)d_in[11];
  const float* bl        = (const float*)d_in[12];
  const float* Wr        = (const float*)d_in[13];
  const float* br        = (const float*)d_in[14];
  const float* att       = (const float*)d_in[15];
  const float* bias_gat  = (const float*)d_in[16];
  const float* W2_nn     = (const float*)d_in[17];
  const float* b2_nn     = (const float*)d_in[18];
  const float* root2     = (const float*)d_in[19];
  const float* bias2     = (const float*)d_in[20];
  const float* Wlin      = (const float*)d_in[21];
  const float* blin      = (const float*)d_in[22];
  float* out = (float*)d_out;

  float* ws = (float*)d_ws;
  float* h0h2  = ws;                 // NN*32 (h0, later h2)
  float* easlab = h0h2 + NN * 32;    // NE*32 floats reserved; bf16 ea in half
  __hip_bfloat16* eab = (__hip_bfloat16*)easlab;     // NE*32 bf16
  float* r1pre = easlab + NE * 32;   // NN*32
  float* xl    = r1pre + NN * 32;    // NN*32
  float* xr    = xl + NN * 32;       // NN*32
  float* mslab = xr + NN * 32;       // NE*32 floats reserved; bf16 msgbuf
  __hip_bfloat16* msgbuf = (__hip_bfloat16*)mslab;   // NE*32 bf16 (CSR order)
  float* fend  = mslab + NE * 32;
  __hip_bfloat16* Bswz1 = (__hip_bfloat16*)fend;            // 33792 bf16
  __hip_bfloat16* Bswz2 = (__hip_bfloat16*)(fend + 17000);  // 33792 bf16
  int* deg    = (int*)(fend + 34000);   // NN
  int* off    = deg + NN;               // NN
  int* cursor = off + NN;               // NN
  int* bsum   = cursor + NN;            // 128
  int* perm   = bsum + 128;             // NE
  int* srcs   = perm + NE;              // NE

  const int B = 256;
  k_zero<<<NBN, B, 0, stream>>>(deg);
  k_prep<<<NBN + NBE + NBP + NBC, B, 0, stream>>>(
      x, edge_attr, ei, We_node, be_node, We_edge, be_edge, root1, bias1,
      W1_nn, b1_nn, W2_nn, b2_nn, h0h2, r1pre, eab, Bswz1, Bswz2, deg);
  k_scan1<<<NBN, B, 0, stream>>>(deg, bsum);
  k_scan3<<<NBN, B, 0, stream>>>(deg, bsum, off, cursor);
  k_csr_fill<<<(NE + B - 1) / B, B, 0, stream>>>(ei, cursor, perm, srcs);
  k_nnconv_mfma<<<512, B, 65536, stream>>>(h0h2, eab, Bswz1, ei, perm, msgbuf);
  k_node1<<<(8 * NN + B - 1) / B, B, 0, stream>>>(r1pre, msgbuf, off, deg, Wl, bl, Wr, br, xl, xr);
  k_gat_node<<<(8 * NN + B - 1) / B, B, 0, stream>>>(srcs, xl, xr, off, deg, att, bias_gat, h0h2);
  k_nnconv_mfma<<<512, B, 65536, stream>>>(h0h2, eab, Bswz2, ei, perm, msgbuf);
  k_node2<<<(8 * NN + B - 1) / B, B, 0, stream>>>(h0h2, msgbuf, off, deg, root2, bias2, Wlin, blin, out);
}